// Round 1
// 314.117 us; speedup vs baseline: 1.0609x; 1.0609x over previous
//
#include <hip/hip_runtime.h>
#include <hip/hip_bf16.h>

#define H  4096
#define V  4
#define OUT_N 4
#define MS 104
#define MD 3

__device__ __forceinline__ float b2f(unsigned short u) {
    return __uint_as_float(((unsigned int)u) << 16);
}
// Load element i of tensor p as float, interpreting storage per flag.
__device__ __forceinline__ float ldf(const void* p, size_t i, bool is_f32) {
    return is_f32 ? ((const float*)p)[i] : b2f(((const unsigned short*)p)[i]);
}
__device__ __forceinline__ void stf(void* p, size_t i, bool is_f32, float v) {
    if (is_f32) ((float*)p)[i] = v;
    else        ((__hip_bfloat16*)p)[i] = __float2bfloat16(v);
}

// ---------------------------------------------------------------------------
// Inline wave-uniform dtype detection (replaces the old detect_kernel launch).
// Decode first 1024 ushorts of w_hh as bf16: real bf16 weights are all
// |x| <~ 0.2; f32 storage puts random-exponent halves there (42%/elem chance
// of |x|>1e6) -> certain to trip over 1024 samples. Ballot makes the result
// wave-uniform; every wave computes the same value (2 KB, L1-hot after wave 0).
// ---------------------------------------------------------------------------
__device__ __forceinline__ bool detect_f32(const void* w_hh) {
    const unsigned short* w = (const unsigned short*)w_hh;
    const int lane = threadIdx.x & 63;
    int bad = 0;
    #pragma unroll
    for (int i = 0; i < 16; ++i) {
        const float v = b2f(w[lane + (i << 6)]);
        if (!(fabsf(v) < 1.0e6f)) bad = 1;   // catches inf/NaN bit patterns too
    }
    return __ballot(bad) != 0ull;
}

// 8 bf16 (as uint4) dotted against 8 f32 (two float4). Little-endian: low
// ushort of a.x is element 0 -> float is (u<<16); high ushort is (u&0xffff0000).
__device__ __forceinline__ float dot8(uint4 a, float4 h0, float4 h1) {
    return __uint_as_float(a.x << 16)          * h0.x
         + __uint_as_float(a.x & 0xffff0000u)  * h0.y
         + __uint_as_float(a.y << 16)          * h0.z
         + __uint_as_float(a.y & 0xffff0000u)  * h0.w
         + __uint_as_float(a.z << 16)          * h1.x
         + __uint_as_float(a.z & 0xffff0000u)  * h1.y
         + __uint_as_float(a.w << 16)          * h1.z
         + __uint_as_float(a.w & 0xffff0000u)  * h1.w;
}

// ---------------------------------------------------------------------------
// h_bar[j] = w_sh[j,:] . stack[0,:] + b_sh[j] + hidden0[j]   (fp32 into ws)
// 80 KB total traffic — launch-overhead scale.
// ---------------------------------------------------------------------------
__global__ __launch_bounds__(256) void hbar_kernel(
    const void* __restrict__ w_sh, const void* __restrict__ b_sh,
    const void* __restrict__ hidden0, const void* __restrict__ stack,
    const void* __restrict__ w_hh, float* __restrict__ h_bar) {
    const bool f32 = detect_f32(w_hh);
    const float s0 = ldf(stack, 0, f32);
    const float s1 = ldf(stack, 1, f32);
    const float s2 = ldf(stack, 2, f32);
    const int j = blockIdx.x * 256 + threadIdx.x;   // grid is exactly H/256
    h_bar[j] = ldf(w_sh, (size_t)j * 3 + 0, f32) * s0
             + ldf(w_sh, (size_t)j * 3 + 1, f32) * s1
             + ldf(w_sh, (size_t)j * 3 + 2, f32) * s2
             + ldf(b_sh, j, f32) + ldf(hidden0, j, f32);
}

// ---------------------------------------------------------------------------
// One WAVE per hidden index k: three w_hh row-dots vs h_bar with 16 B/lane
// vector loads (float4 for f32 storage, uint4 = 8 bf16 for bf16 storage),
// shuffle-reduce, then lane 0 finishes the GRU gates. 1024 blocks x 4 waves.
// Row base byte offsets are k*H*{4,2} = 16 KB / 8 KB aligned -> 16 B loads ok.
// ---------------------------------------------------------------------------
__global__ __launch_bounds__(256) void gru_kernel(
    const int*  __restrict__ inp,  const void* __restrict__ emb,
    const void* __restrict__ w_ih, const void* __restrict__ w_hh,
    const void* __restrict__ b_ih, const void* __restrict__ b_hh,
    const float* __restrict__ h_bar, float* __restrict__ h_f32,
    void* __restrict__ out) {
    const bool f32 = detect_f32(w_hh);
    const int wave = threadIdx.x >> 6, lane = threadIdx.x & 63;
    const int k = (blockIdx.x << 2) + wave;

    float ar = 0.f, az = 0.f, an = 0.f;
    if (f32) {
        const float4* W  = (const float4*)w_hh;
        const float4* HB = (const float4*)h_bar;
        const size_t q0 = (size_t)k           * (H / 4);
        const size_t q1 = (size_t)(k + H)     * (H / 4);
        const size_t q2 = (size_t)(k + 2 * H) * (H / 4);
        #pragma unroll 4
        for (int it = 0; it < H / 256; ++it) {        // 16 iters
            const int i = (it << 6) + lane;
            const float4 hb = HB[i];
            const float4 a = W[q0 + i];
            const float4 b = W[q1 + i];
            const float4 c = W[q2 + i];
            ar += a.x * hb.x + a.y * hb.y + a.z * hb.z + a.w * hb.w;
            az += b.x * hb.x + b.y * hb.y + b.z * hb.z + b.w * hb.w;
            an += c.x * hb.x + c.y * hb.y + c.z * hb.z + c.w * hb.w;
        }
    } else {
        const uint4*  W  = (const uint4*)w_hh;        // 8 bf16 per uint4
        const float4* HB = (const float4*)h_bar;
        const size_t q0 = (size_t)k           * (H / 8);
        const size_t q1 = (size_t)(k + H)     * (H / 8);
        const size_t q2 = (size_t)(k + 2 * H) * (H / 8);
        #pragma unroll 2
        for (int it = 0; it < H / 512; ++it) {        // 8 iters
            const int i = (it << 6) + lane;
            const float4 h0 = HB[2 * i], h1 = HB[2 * i + 1];
            ar += dot8(W[q0 + i], h0, h1);
            az += dot8(W[q1 + i], h0, h1);
            an += dot8(W[q2 + i], h0, h1);
        }
    }

    #pragma unroll
    for (int off = 32; off > 0; off >>= 1) {
        ar += __shfl_down(ar, off);
        az += __shfl_down(az, off);
        an += __shfl_down(an, off);
    }

    if (lane == 0) {
        const int idx = inp[0];
        float x[V];
        #pragma unroll
        for (int c = 0; c < V; ++c) x[c] = ldf(emb, (size_t)idx * V + c, f32);

        float gi[3];
        #pragma unroll
        for (int g = 0; g < 3; ++g) {
            float acc = ldf(b_ih, (size_t)(k + g * H), f32);
            #pragma unroll
            for (int c = 0; c < V; ++c)
                acc += ldf(w_ih, (size_t)(k + g * H) * V + c, f32) * x[c];
            gi[g] = acc;
        }
        const float ghr = ar + ldf(b_hh, (size_t)k,           f32);
        const float ghz = az + ldf(b_hh, (size_t)(k + H),     f32);
        const float ghn = an + ldf(b_hh, (size_t)(k + 2 * H), f32);

        const float r = 1.f / (1.f + expf(-(gi[0] + ghr)));
        const float z = 1.f / (1.f + expf(-(gi[1] + ghz)));
        const float n = tanhf(gi[2] + r * ghn);
        const float hk = (1.f - z) * n + z * h_bar[k];

        h_f32[k] = hk;
        stf(out, (size_t)(OUT_N + k), f32, hk);   // hidden output
    }
}

// ---------------------------------------------------------------------------
// Heads: one row-dot per WAVE (9 of 16 waves active), single barrier, then
// sigmoid/softmax + differentiable stack blend. 144 KB cold reads.
// ---------------------------------------------------------------------------
__global__ __launch_bounds__(1024) void heads_kernel(
    const float* __restrict__ h,
    const void* __restrict__ w_y, const void* __restrict__ b_y,
    const void* __restrict__ w_a, const void* __restrict__ b_a,
    const void* __restrict__ w_n, const void* __restrict__ b_n,
    const void* __restrict__ stack, const void* __restrict__ w_hh,
    void* __restrict__ out) {
    const bool f32 = detect_f32(w_hh);
    const int t = threadIdx.x, wave = t >> 6, lane = t & 63;

    __shared__ float scal[9];
    if (wave < 9) {
        const void* base; size_t row;
        if (wave < 4)      { base = w_y; row = (size_t)wave * H; }
        else if (wave < 6) { base = w_a; row = (size_t)(wave - 4) * H; }
        else               { base = w_n; row = (size_t)(wave - 6) * H; }

        float acc = 0.f;
        if (f32) {
            const float4* W  = (const float4*)((const float*)base + row);
            const float4* Hv = (const float4*)h;
            #pragma unroll 4
            for (int it = 0; it < H / 256; ++it) {
                const int i = (it << 6) + lane;
                const float4 a = W[i], hb = Hv[i];
                acc += a.x * hb.x + a.y * hb.y + a.z * hb.z + a.w * hb.w;
            }
        } else {
            const uint4*  W  = (const uint4*)((const unsigned short*)base + row);
            const float4* Hv = (const float4*)h;
            #pragma unroll 2
            for (int it = 0; it < H / 512; ++it) {
                const int i = (it << 6) + lane;
                acc += dot8(W[i], Hv[2 * i], Hv[2 * i + 1]);
            }
        }
        #pragma unroll
        for (int off = 32; off > 0; off >>= 1) acc += __shfl_down(acc, off);
        if (lane == 0) scal[wave] = acc;
    }
    __syncthreads();

    __shared__ float act0, act1, ne[MD];
    if (t == 0) {
        const float a0 = scal[4] + ldf(b_a, 0, f32);
        const float a1 = scal[5] + ldf(b_a, 1, f32);
        const float m  = fmaxf(a0, a1);
        const float e0 = expf(a0 - m), e1 = expf(a1 - m);
        const float inv = 1.f / (e0 + e1);
        act0 = e0 * inv; act1 = e1 * inv;
    }
    if (t < OUT_N)
        stf(out, (size_t)t, f32,
            1.f / (1.f + expf(-(scal[t] + ldf(b_y, t, f32)))));
    if (t < MD)
        ne[t] = 1.f / (1.f + expf(-(scal[6 + t] + ldf(b_n, t, f32))));
    __syncthreads();

    const float a0 = act0, a1 = act1;
    for (int idx = t; idx < MS * MD; idx += 1024) {
        const int i = idx / MD;
        const int d = idx - i * MD;
        const float push = (i == 0)      ? ne[d] : ldf(stack, (size_t)(idx - MD), f32);
        const float pop  = (i == MS - 1) ? 0.f   : ldf(stack, (size_t)(idx + MD), f32);
        stf(out, (size_t)(OUT_N + H + idx), f32, a0 * push + a1 * pop);
    }
}

extern "C" void kernel_launch(void* const* d_in, const int* in_sizes, int n_in,
                              void* d_out, int out_size, void* d_ws, size_t ws_size,
                              hipStream_t stream) {
    const int* inp      = (const int*)d_in[0];
    const void* hidden0 = d_in[1];
    const void* stack   = d_in[2];
    const void* emb     = d_in[3];
    const void* w_ih    = d_in[4];
    const void* w_hh    = d_in[5];
    const void* b_ih    = d_in[6];
    const void* b_hh    = d_in[7];
    const void* w_y     = d_in[8];
    const void* b_y     = d_in[9];
    const void* w_n     = d_in[10];
    const void* b_n     = d_in[11];
    const void* w_a     = d_in[12];
    const void* b_a     = d_in[13];
    const void* w_sh    = d_in[14];
    const void* b_sh    = d_in[15];

    float* h_bar = (float*)d_ws;          // H fp32 (16 B aligned: hipMalloc)
    float* h     = h_bar + H;             // H fp32

    hbar_kernel<<<H / 256, 256, 0, stream>>>(w_sh, b_sh, hidden0, stack,
                                             w_hh, h_bar);
    gru_kernel<<<H / 4, 256, 0, stream>>>(inp, emb, w_ih, w_hh, b_ih, b_hh,
                                          h_bar, h, d_out);
    heads_kernel<<<1, 1024, 0, stream>>>(h, w_y, b_y, w_a, b_a, w_n, b_n,
                                         stack, w_hh, d_out);
}